// Round 4
// baseline (184.071 us; speedup 1.0000x reference)
//
#include <hip/hip_runtime.h>

#define B_   8
#define C_   256
#define W_   8192
#define F_   256
#define KK   3
#define KC   768            // KK * C_
#define WP   (W_ + 2)       // padded rows in featT (zero row at w=-1 and w=W)
#define COEF 0.03608439182435161f   // 1/sqrt(3*256)
#define BK   32             // K-elements per LDS tile row (64 B, 4 chunks of 16 B)
#define NIT  24             // KC / BK

using f32x16 = __attribute__((ext_vector_type(16))) float;
using bf16x8 = __attribute__((ext_vector_type(8))) __bf16;

#define AS1(p) ((const __attribute__((address_space(1))) void*)(p))
#define AS3(p) ((__attribute__((address_space(3))) void*)(p))

__device__ __forceinline__ unsigned short f2bf(float x) {
    union { float f; unsigned int u; } v; v.f = x;
    unsigned int u = v.u;
    u += 0x7FFFu + ((u >> 16) & 1u);   // RNE
    return (unsigned short)(u >> 16);
}

// kT[f][k*256+c] = bf16(kernel[k][c][f] * COEF); also zeroes featT's pad rows.
__global__ void prep_kt(const float* __restrict__ kern, unsigned short* __restrict__ kT,
                        unsigned short* __restrict__ featT) {
    int idx = blockIdx.x * 256 + threadIdx.x;   // ((k*256)+c)*256 + f
    int f  = idx & 255;
    int kc = idx >> 8;
    kT[(size_t)f * KC + kc] = f2bf(kern[idx] * COEF);
    if (idx < 4096) {       // 8 b * 2 rows * 256 c pad elements
        int b = idx >> 9, r = (idx >> 8) & 1, c = idx & 255;
        size_t row = r ? (size_t)(WP - 1) : 0;
        featT[((size_t)b * WP + row) * C_ + c] = 0;
    }
}

// denom[b][f] = rsqrt( sum_{k,c} (kernel[k,c,f]*COEF*(style[b,c]+1))^2 )
__global__ __launch_bounds__(256) void prep_denom(const float* __restrict__ kern,
                                                  const float* __restrict__ style,
                                                  float* __restrict__ denom) {
    __shared__ float sst[C_];
    const int b = blockIdx.x, f = threadIdx.x;
    sst[f] = (style[b * C_ + f] + 1.0f) * COEF;
    __syncthreads();
    float sum = 0.f;
#pragma unroll 8
    for (int kc = 0; kc < KC; ++kc) {
        float w = kern[(size_t)kc * F_ + f] * sst[kc & 255];
        sum += w * w;
    }
    denom[b * F_ + f] = rsqrtf(sum);
}

// featT[b][w+1][c] = bf16( feat[b][c][w] * (style[b][c]+1) )
__global__ __launch_bounds__(256) void prep_featT(const float* __restrict__ feat,
                                                  const float* __restrict__ style,
                                                  unsigned short* __restrict__ featT) {
    __shared__ float tile[64][65];   // [w][c]
    const int tid = threadIdx.x;
    const int b = blockIdx.z, c0 = blockIdx.y * 64, w0 = blockIdx.x * 64;

    const int x4 = tid & 15, cl4 = tid >> 4;
#pragma unroll
    for (int p = 0; p < 4; ++p) {
        const int cl = cl4 + p * 16;
        const float s = style[b * C_ + c0 + cl] + 1.0f;
        float4 v = *(const float4*)(feat + ((size_t)b * C_ + c0 + cl) * W_ + w0 + x4 * 4);
        tile[x4 * 4 + 0][cl] = v.x * s;
        tile[x4 * 4 + 1][cl] = v.y * s;
        tile[x4 * 4 + 2][cl] = v.z * s;
        tile[x4 * 4 + 3][cl] = v.w * s;
    }
    __syncthreads();

    const int ch = tid & 7, wr = tid >> 3;   // ch: 8-c chunk, wr: 0..31
#pragma unroll
    for (int p = 0; p < 2; ++p) {
        const int w = wr + p * 32;
        unsigned int pk[4];
#pragma unroll
        for (int j = 0; j < 4; ++j) {
            float v0 = tile[w][ch * 8 + 2 * j];
            float v1 = tile[w][ch * 8 + 2 * j + 1];
            pk[j] = (unsigned int)f2bf(v0) | ((unsigned int)f2bf(v1) << 16);
        }
        uint4 u; u.x = pk[0]; u.y = pk[1]; u.z = pk[2]; u.w = pk[3];
        *(uint4*)(featT + ((size_t)b * WP + (w0 + w + 1)) * C_ + c0 + ch * 8) = u;
    }
}

// Main: block = 256(f) x 128(w), 4 waves each 64(f) x 128(w) via 2x4 of 32x32x16 MFMA.
// BK=32, 24 iters, double-buffered LDS, ONE barrier per iter: stage buf[t+1] after
// the barrier, MFMA on buf[t] -> the compiler's vmcnt(0)-before-barrier drain waits
// on loads that had a full MFMA phase in flight.
__global__ __launch_bounds__(256, 2) void conv_mod(
        const unsigned short* __restrict__ featT,
        const unsigned short* __restrict__ kT,
        const float* __restrict__ denom,
        float* __restrict__ out) {
    __shared__ unsigned short As[2 * 256 * BK];  // 16 KB per buffer
    __shared__ unsigned short Bs[2 * 128 * BK];  //  8 KB per buffer

    const int tid  = threadIdx.x;
    const int b    = blockIdx.z;
    const int w0   = blockIdx.x * 128;
    const int lane = tid & 63, wave = tid >> 6;
    const int la   = lane & 31, kq = lane >> 5;

    // ---- staging setup: per instruction, lane covers row base + (l>>2), phys chunk l&3,
    //      source logical chunk (l&3)^((l>>2)&3)  (XOR swizzle on the GLOBAL address) ----
    const int lrow = lane >> 2, lswz = (lane & 3) ^ (lrow & 3);
    const unsigned short* asrc[4];  int aldb[4];   // A: 4 insts/wave, 16 rows each
    const unsigned short* bsrc[2];  int bldb[2];   // B: 2 insts/wave
#pragma unroll
    for (int j = 0; j < 4; ++j) {
        const int r = wave * 64 + j * 16;
        asrc[j] = kT + (size_t)(r + lrow) * KC + lswz * 8;
        aldb[j] = r * BK;
    }
#pragma unroll
    for (int j = 0; j < 2; ++j) {
        const int r = wave * 32 + j * 16;
        bsrc[j] = featT + ((size_t)b * WP + (w0 + r + lrow)) * C_ + lswz * 8;
        bldb[j] = r * BK;
    }

    // ---- fragment LDS offsets (ushort indices); chunk = (s*2+kq) ^ (la&3) ----
    int ch[2];
#pragma unroll
    for (int s = 0; s < 2; ++s) ch[s] = ((s * 2 + kq) ^ (la & 3)) * 8;
    int aoff[2][2], boff[4][2];
#pragma unroll
    for (int mi = 0; mi < 2; ++mi)
#pragma unroll
        for (int s = 0; s < 2; ++s)
            aoff[mi][s] = (wave * 64 + mi * 32 + la) * BK + ch[s];
#pragma unroll
    for (int ni = 0; ni < 4; ++ni)
#pragma unroll
        for (int s = 0; s < 2; ++s)
            boff[ni][s] = (ni * 32 + la) * BK + ch[s];

    f32x16 acc[2][4] = {};

    // prologue: stage buffer 0
#pragma unroll
    for (int j = 0; j < 4; ++j)
        __builtin_amdgcn_global_load_lds(AS1(asrc[j]), AS3(&As[aldb[j]]), 16, 0, 0);
#pragma unroll
    for (int j = 0; j < 2; ++j)
        __builtin_amdgcn_global_load_lds(AS1(bsrc[j]), AS3(&Bs[bldb[j]]), 16, 0, 0);

#pragma unroll 2
    for (int it = 0; it < NIT; ++it) {
        const int cur = (it & 1);
        __syncthreads();   // drains buf[cur] staging (in flight one full MFMA phase)
        if (it + 1 < NIT) {
            const int nxt = cur ^ 1;
            const int kc = (it + 1) * BK;
#pragma unroll
            for (int j = 0; j < 4; ++j)
                __builtin_amdgcn_global_load_lds(AS1(asrc[j] + kc),
                                                 AS3(&As[nxt * 256 * BK + aldb[j]]), 16, 0, 0);
#pragma unroll
            for (int j = 0; j < 2; ++j)
                __builtin_amdgcn_global_load_lds(AS1(bsrc[j] + kc),
                                                 AS3(&Bs[nxt * 128 * BK + bldb[j]]), 16, 0, 0);
        }
        const unsigned short* Ab = &As[cur * 256 * BK];
        const unsigned short* Bb = &Bs[cur * 128 * BK];
#pragma unroll
        for (int s = 0; s < 2; ++s) {
            bf16x8 aF[2], bF[4];
#pragma unroll
            for (int mi = 0; mi < 2; ++mi) aF[mi] = *(const bf16x8*)&Ab[aoff[mi][s]];
#pragma unroll
            for (int ni = 0; ni < 4; ++ni) bF[ni] = *(const bf16x8*)&Bb[boff[ni][s]];
#pragma unroll
            for (int mi = 0; mi < 2; ++mi)
#pragma unroll
                for (int ni = 0; ni < 4; ++ni)
                    acc[mi][ni] = __builtin_amdgcn_mfma_f32_32x32x16_bf16(
                        aF[mi], bF[ni], acc[mi][ni], 0, 0, 0);
        }
    }

    // ---- epilogue: C/D 32x32 layout: col=lane&31, row=(reg&3)+8*(reg>>2)+4*(lane>>5) ----
    const int bofs = b * F_;
#pragma unroll
    for (int mi = 0; mi < 2; ++mi) {
#pragma unroll
        for (int r = 0; r < 16; ++r) {
            const int frow = (r & 3) + 8 * (r >> 2) + 4 * kq;
            const int f = wave * 64 + mi * 32 + frow;
            const float d = denom[bofs + f];
            float* orow = out + (size_t)(bofs + f) * W_ + w0 + la;
            orow[0]  = acc[mi][0][r] * d;
            orow[32] = acc[mi][1][r] * d;
            orow[64] = acc[mi][2][r] * d;
            orow[96] = acc[mi][3][r] * d;
        }
    }
}

extern "C" void kernel_launch(void* const* d_in, const int* in_sizes, int n_in,
                              void* d_out, int out_size, void* d_ws, size_t ws_size,
                              hipStream_t stream) {
    const float* feature = (const float*)d_in[0];   // [8,256,8192]
    const float* style   = (const float*)d_in[1];   // [8,256]
    const float* kern    = (const float*)d_in[2];   // [3,256,256]
    float* out = (float*)d_out;                     // [8,256,8192]

    // ws layout: kT (384 KiB) | denom (8 KiB) | featT (8*8194*256 bf16 = 32.0 MiB)
    unsigned short* kT    = (unsigned short*)d_ws;
    float*          denom = (float*)((char*)d_ws + (size_t)F_ * KC * 2);
    unsigned short* featT = (unsigned short*)((char*)d_ws + (size_t)F_ * KC * 2 + 8192);

    hipLaunchKernelGGL(prep_kt,    dim3(KC),     dim3(256), 0, stream, kern, kT, featT);
    hipLaunchKernelGGL(prep_denom, dim3(B_),     dim3(256), 0, stream, kern, style, denom);
    hipLaunchKernelGGL(prep_featT, dim3(W_ / 64, C_ / 64, B_), dim3(256), 0, stream,
                       feature, style, featT);
    hipLaunchKernelGGL(conv_mod,   dim3(W_ / 128, 1, B_), dim3(256), 0, stream,
                       featT, kT, denom, out);
}

// Round 5
// 181.496 us; speedup vs baseline: 1.0142x; 1.0142x over previous
//
#include <hip/hip_runtime.h>

#define B_   8
#define C_   256
#define W_   8192
#define F_   256
#define KK   3
#define KC   768            // KK * C_
#define WP   (W_ + 2)       // padded rows in featT (zero row at w=-1 and w=W)
#define COEF 0.03608439182435161f   // 1/sqrt(3*256)
#define BK   64             // K-elements per LDS tile row (128 B -> bank-position = chunk only)
#define NIT  12             // KC / BK

using f32x16 = __attribute__((ext_vector_type(16))) float;
using bf16x8 = __attribute__((ext_vector_type(8))) __bf16;

#define AS1(p) ((const __attribute__((address_space(1))) void*)(p))
#define AS3(p) ((__attribute__((address_space(3))) void*)(p))

__device__ __forceinline__ unsigned short f2bf(float x) {
    union { float f; unsigned int u; } v; v.f = x;
    unsigned int u = v.u;
    u += 0x7FFFu + ((u >> 16) & 1u);   // RNE
    return (unsigned short)(u >> 16);
}

// kT[f][k*256+c] = bf16(kernel[k][c][f] * COEF); also zeroes featT's pad rows.
__global__ void prep_kt(const float* __restrict__ kern, unsigned short* __restrict__ kT,
                        unsigned short* __restrict__ featT) {
    int idx = blockIdx.x * 256 + threadIdx.x;   // ((k*256)+c)*256 + f
    int f  = idx & 255;
    int kc = idx >> 8;
    kT[(size_t)f * KC + kc] = f2bf(kern[idx] * COEF);
    if (idx < 4096) {       // 8 b * 2 rows * 256 c pad elements
        int b = idx >> 9, r = (idx >> 8) & 1, c = idx & 255;
        size_t row = r ? (size_t)(WP - 1) : 0;
        featT[((size_t)b * WP + row) * C_ + c] = 0;
    }
}

// denom[b][f] = rsqrt( sum_{k,c} (kernel[k,c,f]*COEF*(style[b,c]+1))^2 )
__global__ __launch_bounds__(256) void prep_denom(const float* __restrict__ kern,
                                                  const float* __restrict__ style,
                                                  float* __restrict__ denom) {
    __shared__ float sst[C_];
    const int b = blockIdx.x, f = threadIdx.x;
    sst[f] = (style[b * C_ + f] + 1.0f) * COEF;
    __syncthreads();
    float sum = 0.f;
#pragma unroll 8
    for (int kc = 0; kc < KC; ++kc) {
        float w = kern[(size_t)kc * F_ + f] * sst[kc & 255];
        sum += w * w;
    }
    denom[b * F_ + f] = rsqrtf(sum);
}

// featT[b][w+1][c] = bf16( feat[b][c][w] * (style[b][c]+1) )
__global__ __launch_bounds__(256) void prep_featT(const float* __restrict__ feat,
                                                  const float* __restrict__ style,
                                                  unsigned short* __restrict__ featT) {
    __shared__ float tile[64][65];   // [w][c]
    const int tid = threadIdx.x;
    const int b = blockIdx.z, c0 = blockIdx.y * 64, w0 = blockIdx.x * 64;

    const int x4 = tid & 15, cl4 = tid >> 4;
#pragma unroll
    for (int p = 0; p < 4; ++p) {
        const int cl = cl4 + p * 16;
        const float s = style[b * C_ + c0 + cl] + 1.0f;
        float4 v = *(const float4*)(feat + ((size_t)b * C_ + c0 + cl) * W_ + w0 + x4 * 4);
        tile[x4 * 4 + 0][cl] = v.x * s;
        tile[x4 * 4 + 1][cl] = v.y * s;
        tile[x4 * 4 + 2][cl] = v.z * s;
        tile[x4 * 4 + 3][cl] = v.w * s;
    }
    __syncthreads();

    const int ch = tid & 7, wr = tid >> 3;   // ch: 8-c chunk, wr: 0..31
#pragma unroll
    for (int p = 0; p < 2; ++p) {
        const int w = wr + p * 32;
        unsigned int pk[4];
#pragma unroll
        for (int j = 0; j < 4; ++j) {
            float v0 = tile[w][ch * 8 + 2 * j];
            float v1 = tile[w][ch * 8 + 2 * j + 1];
            pk[j] = (unsigned int)f2bf(v0) | ((unsigned int)f2bf(v1) << 16);
        }
        uint4 u; u.x = pk[0]; u.y = pk[1]; u.z = pk[2]; u.w = pk[3];
        *(uint4*)(featT + ((size_t)b * WP + (w0 + w + 1)) * C_ + c0 + ch * 8) = u;
    }
}

// Main: 128(f) x 128(w) block, 4 waves each 64x64 via 2x2 of 32x32x16 MFMA, BK=64.
// Double-buffered LDS, ONE barrier per iter: stage buf[t+1] after the barrier, MFMA
// on buf[t] -> the vmcnt(0)-before-barrier drain waits on loads that had a full MFMA
// phase in flight. 128-B rows: XOR chunk swizzle is row-invariant mod 32 banks.
__global__ __launch_bounds__(256, 2) void conv_mod(
        const unsigned short* __restrict__ featT,
        const unsigned short* __restrict__ kT,
        const float* __restrict__ denom,
        float* __restrict__ out) {
    __shared__ unsigned short As[2 * 128 * BK];  // 16 KB per buffer
    __shared__ unsigned short Bs[2 * 128 * BK];

    const int tid  = threadIdx.x;
    const int b    = blockIdx.z;
    const int f0   = blockIdx.y * 128;
    const int w0   = blockIdx.x * 128;
    const int lane = tid & 63, wave = tid >> 6;
    const int wm   = (wave >> 1) * 64;   // wave f-offset
    const int wn   = (wave & 1) * 64;    // wave w-offset
    const int la   = lane & 31, kq = lane >> 5;

    // ---- staging: lane covers row base + (l>>3), phys chunk l&7,
    //      source logical chunk (l&7)^(l>>3)  (XOR swizzle on the GLOBAL address) ----
    const int lrow = lane >> 3, lswz = (lane & 7) ^ lrow;
    const unsigned short* asrc[4];
    const unsigned short* bsrc[4];
    int ldb[4];
#pragma unroll
    for (int i = 0; i < 4; ++i) {
        const int r = wave * 32 + i * 8;
        asrc[i] = kT + (size_t)(f0 + r + lrow) * KC + lswz * 8;
        bsrc[i] = featT + ((size_t)b * WP + (w0 + r + lrow)) * C_ + lswz * 8;
        ldb[i]  = r * BK;
    }

    // ---- fragment LDS offsets; phys chunk of logical (kh*2+kq) in row la is ^(la&7) ----
    int aoff[2][4], boff[2][4];
#pragma unroll
    for (int mi = 0; mi < 2; ++mi)
#pragma unroll
        for (int kh = 0; kh < 4; ++kh)
            aoff[mi][kh] = (wm + mi * 32 + la) * BK + ((kh * 2 + kq) ^ (la & 7)) * 8;
#pragma unroll
    for (int ni = 0; ni < 2; ++ni)
#pragma unroll
        for (int kh = 0; kh < 4; ++kh)
            boff[ni][kh] = (wn + ni * 32 + la) * BK + ((kh * 2 + kq) ^ (la & 7)) * 8;

    f32x16 acc[2][2] = {};

    // prologue: stage buffer 0
#pragma unroll
    for (int i = 0; i < 4; ++i) {
        __builtin_amdgcn_global_load_lds(AS1(asrc[i]), AS3(&As[ldb[i]]), 16, 0, 0);
        __builtin_amdgcn_global_load_lds(AS1(bsrc[i]), AS3(&Bs[ldb[i]]), 16, 0, 0);
    }

#pragma unroll 2
    for (int it = 0; it < NIT; ++it) {
        const int cur = it & 1;
        __syncthreads();   // buf[cur] staged (issued one full MFMA phase ago) + prev reads done
        if (it + 1 < NIT) {
            const int nxt = cur ^ 1;
            const int kc = (it + 1) * BK;
#pragma unroll
            for (int i = 0; i < 4; ++i) {
                __builtin_amdgcn_global_load_lds(AS1(asrc[i] + kc),
                                                 AS3(&As[nxt * 128 * BK + ldb[i]]), 16, 0, 0);
                __builtin_amdgcn_global_load_lds(AS1(bsrc[i] + kc),
                                                 AS3(&Bs[nxt * 128 * BK + ldb[i]]), 16, 0, 0);
            }
        }
        const unsigned short* Ab = &As[cur * 128 * BK];
        const unsigned short* Bb = &Bs[cur * 128 * BK];
#pragma unroll
        for (int kh = 0; kh < 4; ++kh) {
            bf16x8 a0 = *(const bf16x8*)&Ab[aoff[0][kh]];
            bf16x8 a1 = *(const bf16x8*)&Ab[aoff[1][kh]];
            bf16x8 b0 = *(const bf16x8*)&Bb[boff[0][kh]];
            bf16x8 b1 = *(const bf16x8*)&Bb[boff[1][kh]];
            acc[0][0] = __builtin_amdgcn_mfma_f32_32x32x16_bf16(a0, b0, acc[0][0], 0, 0, 0);
            acc[0][1] = __builtin_amdgcn_mfma_f32_32x32x16_bf16(a0, b1, acc[0][1], 0, 0, 0);
            acc[1][0] = __builtin_amdgcn_mfma_f32_32x32x16_bf16(a1, b0, acc[1][0], 0, 0, 0);
            acc[1][1] = __builtin_amdgcn_mfma_f32_32x32x16_bf16(a1, b1, acc[1][1], 0, 0, 0);
        }
    }

    // ---- epilogue: C/D 32x32 layout: col=lane&31, row=(reg&3)+8*(reg>>2)+4*(lane>>5) ----
    const int bofs = b * F_;
#pragma unroll
    for (int mi = 0; mi < 2; ++mi) {
#pragma unroll
        for (int r = 0; r < 16; ++r) {
            const int frow = (r & 3) + 8 * (r >> 2) + 4 * kq;
            const int f = f0 + wm + mi * 32 + frow;
            const float d = denom[bofs + f];
            float* orow = out + (size_t)(bofs + f) * W_ + w0 + wn + la;
            orow[0]  = acc[mi][0][r] * d;
            orow[32] = acc[mi][1][r] * d;
        }
    }
}

extern "C" void kernel_launch(void* const* d_in, const int* in_sizes, int n_in,
                              void* d_out, int out_size, void* d_ws, size_t ws_size,
                              hipStream_t stream) {
    const float* feature = (const float*)d_in[0];   // [8,256,8192]
    const float* style   = (const float*)d_in[1];   // [8,256]
    const float* kern    = (const float*)d_in[2];   // [3,256,256]
    float* out = (float*)d_out;                     // [8,256,8192]

    // ws layout: kT (384 KiB) | denom (8 KiB) | featT (8*8194*256 bf16 = 32.0 MiB)
    unsigned short* kT    = (unsigned short*)d_ws;
    float*          denom = (float*)((char*)d_ws + (size_t)F_ * KC * 2);
    unsigned short* featT = (unsigned short*)((char*)d_ws + (size_t)F_ * KC * 2 + 8192);

    hipLaunchKernelGGL(prep_kt,    dim3(KC),     dim3(256), 0, stream, kern, kT, featT);
    hipLaunchKernelGGL(prep_denom, dim3(B_),     dim3(256), 0, stream, kern, style, denom);
    hipLaunchKernelGGL(prep_featT, dim3(W_ / 64, C_ / 64, B_), dim3(256), 0, stream,
                       feature, style, featT);
    hipLaunchKernelGGL(conv_mod,   dim3(W_ / 128, F_ / 128, B_), dim3(256), 0, stream,
                       featT, kT, denom, out);
}